// Round 1
// baseline (262.617 us; speedup 1.0000x reference)
//
#include <hip/hip_runtime.h>

#define NN 30000
#define NE 120000
#define WD 32
#define NK 10   // k=0..7: k_w2 slices, k=8: k_b2, k=9: root

// h0[n,o] = x[n]*fc1_w[o] + fc1_b[o]
__global__ void k_h0(const float* __restrict__ x, const float* __restrict__ fc1w,
                     const float* __restrict__ fc1b, float* __restrict__ h) {
  int t = blockIdx.x * 256 + threadIdx.x;
  if (t >= NN * WD) return;
  int n = t >> 5, o = t & 31;
  h[t] = fmaf(x[n], fc1w[o], fc1b[o]);
}

// kh[e,:] = relu(edge_attr @ k_w1 + k_b1); cnt[dst[e]]++
__global__ void k_prep(const float* __restrict__ ea, const float* __restrict__ w1,
                       const float* __restrict__ b1, const int* __restrict__ dst,
                       float* __restrict__ kh, int* __restrict__ cnt) {
  int e = blockIdx.x * 256 + threadIdx.x;
  if (e >= NE) return;
  float a[6];
#pragma unroll
  for (int i = 0; i < 6; i++) a[i] = ea[e * 6 + i];
#pragma unroll
  for (int k = 0; k < 8; k++) {
    float s = b1[k];
#pragma unroll
    for (int i = 0; i < 6; i++) s = fmaf(a[i], w1[i * 8 + k], s);
    kh[e * 8 + k] = fmaxf(s, 0.f);
  }
  atomicAdd(&cnt[dst[e]], 1);
}

__global__ void k_icnt(const int* __restrict__ cnt, float* __restrict__ icnt) {
  int n = blockIdx.x * 256 + threadIdx.x;
  if (n < NN) icnt[n] = 1.0f / (float)max(cnt[n], 1);
}

// P[n,k,o] = sum_i h[n,i] * Wl[k][i*32+o]; Wl = {k_w2 (k=0..7), k_b2 (k=8), root (k=9)}
__global__ void k_node(const float* __restrict__ h, const float* __restrict__ kw2,
                       const float* __restrict__ kb2, const float* __restrict__ root,
                       float* __restrict__ P) {
  __shared__ float Wl[NK * 1024];
  for (int i = threadIdx.x; i < 8 * 1024; i += 256) Wl[i] = kw2[i];
  for (int i = threadIdx.x; i < 1024; i += 256) {
    Wl[8 * 1024 + i] = kb2[i];
    Wl[9 * 1024 + i] = root[i];
  }
  __syncthreads();
  int n = blockIdx.x * 8 + (threadIdx.x >> 5);
  int o = threadIdx.x & 31;
  float hreg = h[n * WD + o];
  float hv[WD];
#pragma unroll
  for (int i = 0; i < WD; i++) hv[i] = __shfl(hreg, i, WD);
  float* Pn = P + (size_t)n * NK * WD;
#pragma unroll
  for (int k = 0; k < NK; k++) {
    float acc = 0.f;
#pragma unroll
    for (int i = 0; i < WD; i++) acc = fmaf(hv[i], Wl[k * 1024 + i * 32 + o], acc);
    Pn[k * WD + o] = acc;
  }
}

// per edge: msg[o] = P[src,8,o] + sum_k kh[e,k]*P[src,k,o]; atomic scatter to agg[dst]
__global__ void k_edge(const float* __restrict__ P, const float* __restrict__ kh,
                       const int* __restrict__ src, const int* __restrict__ dst,
                       float* __restrict__ agg) {
  int t = blockIdx.x * 256 + threadIdx.x;
  int e = t >> 5;
  int o = t & 31;
  int s = src[e], d = dst[e];
  float kv = (o < 8) ? kh[e * 8 + o] : 0.f;
  const float* Ps = P + (size_t)s * NK * WD;
  float m = Ps[8 * WD + o];
#pragma unroll
  for (int k = 0; k < 8; k++)
    m = fmaf(__shfl(kv, k, WD), Ps[k * WD + o], m);
  atomicAdd(&agg[d * WD + o], m);
}

// h_next = relu(agg*icnt + h@root (=P[:,9,:]) + conv_bias)
__global__ void k_comb(const float* __restrict__ agg, const float* __restrict__ icnt,
                       const float* __restrict__ P, const float* __restrict__ cbias,
                       float* __restrict__ hn) {
  int t = blockIdx.x * 256 + threadIdx.x;
  if (t >= NN * WD) return;
  int n = t >> 5, o = t & 31;
  float v = fmaf(agg[t], icnt[n], P[(size_t)n * NK * WD + 9 * WD + o] + cbias[o]);
  hn[t] = fmaxf(v, 0.f);
}

__global__ void k_out(const float* __restrict__ h, const float* __restrict__ w2,
                      const float* __restrict__ b2, float* __restrict__ out) {
  int n = blockIdx.x * 256 + threadIdx.x;
  if (n >= NN) return;
  float s = b2[0];
#pragma unroll
  for (int o = 0; o < WD; o++) s = fmaf(h[n * WD + o], w2[o], s);
  out[n] = s;
}

extern "C" void kernel_launch(void* const* d_in, const int* in_sizes, int n_in,
                              void* d_out, int out_size, void* d_ws, size_t ws_size,
                              hipStream_t stream) {
  const float* x     = (const float*)d_in[0];
  const int*   ei    = (const int*)d_in[1];
  const float* ea    = (const float*)d_in[2];
  const float* fc1w  = (const float*)d_in[3];
  const float* fc1b  = (const float*)d_in[4];
  const float* kw1   = (const float*)d_in[5];
  const float* kb1   = (const float*)d_in[6];
  const float* kw2   = (const float*)d_in[7];
  const float* kb2   = (const float*)d_in[8];
  const float* root  = (const float*)d_in[9];
  const float* cbias = (const float*)d_in[10];
  const float* fc2w  = (const float*)d_in[11];
  const float* fc2b  = (const float*)d_in[12];
  float* out = (float*)d_out;

  float* ws   = (float*)d_ws;
  float* h_a  = ws;                       // NN*WD
  float* h_b  = h_a + NN * WD;            // NN*WD
  float* kh   = h_b + NN * WD;            // NE*8
  float* P    = kh + NE * 8;              // NN*NK*WD
  float* agg  = P + (size_t)NN * NK * WD; // NN*WD
  float* icnt = agg + NN * WD;            // NN
  int*   cnt  = (int*)(icnt + NN);        // NN

  const int* srcp = ei;       // edge_index[0]
  const int* dstp = ei + NE;  // edge_index[1]

  hipMemsetAsync(cnt, 0, NN * sizeof(int), stream);
  k_h0<<<(NN * WD + 255) / 256, 256, 0, stream>>>(x, fc1w, fc1b, h_a);
  k_prep<<<(NE + 255) / 256, 256, 0, stream>>>(ea, kw1, kb1, dstp, kh, cnt);
  k_icnt<<<(NN + 255) / 256, 256, 0, stream>>>(cnt, icnt);

  float* hc = h_a;
  float* hn = h_b;
  for (int l = 0; l < 4; l++) {
    k_node<<<NN / 8, 256, 0, stream>>>(hc, kw2, kb2, root, P);
    hipMemsetAsync(agg, 0, NN * WD * sizeof(float), stream);
    k_edge<<<NE * WD / 256, 256, 0, stream>>>(P, kh, srcp, dstp, agg);
    k_comb<<<(NN * WD + 255) / 256, 256, 0, stream>>>(agg, icnt, P, cbias, hn);
    float* tmp = hc; hc = hn; hn = tmp;
  }
  k_out<<<(NN + 255) / 256, 256, 0, stream>>>(hc, fc2w, fc2b, out);
}

// Round 2
// 237.644 us; speedup vs baseline: 1.1051x; 1.1051x over previous
//
#include <hip/hip_runtime.h>

#define NN 30000
#define NE 120000
#define WD 32
#define NK 10   // k=0..7: k_w2 slices, k=8: k_b2, k=9: root

__global__ void k_zero_cnt(int* __restrict__ cnt) {
  int n = blockIdx.x * 256 + threadIdx.x;
  if (n < NN) cnt[n] = 0;
}

// kh[e,:] = relu(edge_attr @ k_w1 + k_b1); cnt[dst[e]]++
__global__ void k_prep(const float* __restrict__ ea, const float* __restrict__ w1,
                       const float* __restrict__ b1, const int* __restrict__ dst,
                       float* __restrict__ kh, int* __restrict__ cnt) {
  int e = blockIdx.x * 256 + threadIdx.x;
  if (e >= NE) return;
  float a[6];
#pragma unroll
  for (int i = 0; i < 6; i++) a[i] = ea[e * 6 + i];
#pragma unroll
  for (int k = 0; k < 8; k++) {
    float s = b1[k];
#pragma unroll
    for (int i = 0; i < 6; i++) s = fmaf(a[i], w1[i * 8 + k], s);
    kh[e * 8 + k] = fmaxf(s, 0.f);
  }
  atomicAdd(&cnt[dst[e]], 1);
}

// Node transform. FIRST: h = x*fc1w + fc1b. Else: h = relu(agg/cnt + P[:,9] + cbias).
// Writes P[n,k,o] = sum_i h[n,i]*Wl[k][i*32+o] for k=0..9, and zeroes agg[n,:].
template <bool FIRST>
__global__ void k_node(const float* __restrict__ x, const float* __restrict__ fc1w,
                       const float* __restrict__ fc1b, const int* __restrict__ cnt,
                       const float* __restrict__ cbias, const float* __restrict__ kw2,
                       const float* __restrict__ kb2, const float* __restrict__ root,
                       float* __restrict__ agg, float* __restrict__ P) {
  __shared__ float Wl[NK * 1024];
  for (int i = threadIdx.x; i < 8 * 1024; i += 256) Wl[i] = kw2[i];
  for (int i = threadIdx.x; i < 1024; i += 256) {
    Wl[8 * 1024 + i] = kb2[i];
    Wl[9 * 1024 + i] = root[i];
  }
  __syncthreads();
  int g = threadIdx.x >> 5;  // node-group 0..7
  int o = threadIdx.x & 31;
  int base = blockIdx.x * 32;  // 32 nodes per block
#pragma unroll
  for (int r = 0; r < 4; r++) {
    int n = base + r * 8 + g;
    if (n < NN) {
      float hreg;
      if (FIRST) {
        hreg = fmaf(x[n], fc1w[o], fc1b[o]);
      } else {
        float ic = 1.0f / (float)max(cnt[n], 1);
        float v = fmaf(agg[n * WD + o], ic,
                       P[(size_t)n * NK * WD + 9 * WD + o] + cbias[o]);
        hreg = fmaxf(v, 0.f);
      }
      agg[n * WD + o] = 0.f;  // pre-zero for the upcoming edge scatter
      float hv[WD];
#pragma unroll
      for (int i = 0; i < WD; i++) hv[i] = __shfl(hreg, i, WD);
      float* Pn = P + (size_t)n * NK * WD;
#pragma unroll
      for (int k = 0; k < NK; k++) {
        float acc = 0.f;
#pragma unroll
        for (int i = 0; i < WD; i++)
          acc = fmaf(hv[i], Wl[k * 1024 + i * 32 + o], acc);
        Pn[k * WD + o] = acc;
      }
    }
  }
}

// per edge: msg[o] = P[src,8,o] + sum_k kh[e,k]*P[src,k,o]; atomic scatter to agg[dst]
__global__ void k_edge(const float* __restrict__ P, const float* __restrict__ kh,
                       const int* __restrict__ src, const int* __restrict__ dst,
                       float* __restrict__ agg) {
  int t = blockIdx.x * 256 + threadIdx.x;
  int e = t >> 5;
  int o = t & 31;
  int s = src[e], d = dst[e];
  float kv = (o < 8) ? kh[e * 8 + o] : 0.f;
  const float* Ps = P + (size_t)s * NK * WD;
  float m = Ps[8 * WD + o];
#pragma unroll
  for (int k = 0; k < 8; k++)
    m = fmaf(__shfl(kv, k, WD), Ps[k * WD + o], m);
  atomicAdd(&agg[d * WD + o], m);
}

// final: h4 = relu(agg/cnt + P[:,9] + cbias); out[n] = h4 @ fc2w + fc2b
__global__ void k_out(const float* __restrict__ agg, const int* __restrict__ cnt,
                      const float* __restrict__ P, const float* __restrict__ cbias,
                      const float* __restrict__ fc2w, const float* __restrict__ fc2b,
                      float* __restrict__ out) {
  int t = blockIdx.x * 256 + threadIdx.x;
  int n = t >> 5, o = t & 31;
  if (n >= NN) return;
  float ic = 1.0f / (float)max(cnt[n], 1);
  float h = fmaxf(fmaf(agg[t], ic, P[(size_t)n * NK * WD + 9 * WD + o] + cbias[o]), 0.f);
  float s = h * fc2w[o];
#pragma unroll
  for (int d = 16; d; d >>= 1) s += __shfl_xor(s, d, 32);
  if (o == 0) out[n] = s + fc2b[0];
}

extern "C" void kernel_launch(void* const* d_in, const int* in_sizes, int n_in,
                              void* d_out, int out_size, void* d_ws, size_t ws_size,
                              hipStream_t stream) {
  const float* x     = (const float*)d_in[0];
  const int*   ei    = (const int*)d_in[1];
  const float* ea    = (const float*)d_in[2];
  const float* fc1w  = (const float*)d_in[3];
  const float* fc1b  = (const float*)d_in[4];
  const float* kw1   = (const float*)d_in[5];
  const float* kb1   = (const float*)d_in[6];
  const float* kw2   = (const float*)d_in[7];
  const float* kb2   = (const float*)d_in[8];
  const float* root  = (const float*)d_in[9];
  const float* cbias = (const float*)d_in[10];
  const float* fc2w  = (const float*)d_in[11];
  const float* fc2b  = (const float*)d_in[12];
  float* out = (float*)d_out;

  float* ws  = (float*)d_ws;
  float* kh  = ws;                         // NE*8
  float* P   = kh + NE * 8;                // NN*NK*WD
  float* agg = P + (size_t)NN * NK * WD;   // NN*WD
  int*   cnt = (int*)(agg + NN * WD);      // NN

  const int* srcp = ei;       // edge_index[0]
  const int* dstp = ei + NE;  // edge_index[1]

  k_zero_cnt<<<(NN + 255) / 256, 256, 0, stream>>>(cnt);
  k_prep<<<(NE + 255) / 256, 256, 0, stream>>>(ea, kw1, kb1, dstp, kh, cnt);

  const int node_grid = (NN + 31) / 32;
  for (int l = 0; l < 4; l++) {
    if (l == 0)
      k_node<true><<<node_grid, 256, 0, stream>>>(x, fc1w, fc1b, cnt, cbias, kw2,
                                                  kb2, root, agg, P);
    else
      k_node<false><<<node_grid, 256, 0, stream>>>(x, fc1w, fc1b, cnt, cbias, kw2,
                                                   kb2, root, agg, P);
    k_edge<<<NE * WD / 256, 256, 0, stream>>>(P, kh, srcp, dstp, agg);
  }
  k_out<<<(NN * WD + 255) / 256, 256, 0, stream>>>(agg, cnt, P, cbias, fc2w, fc2b, out);
}